// Round 4
// baseline (40.944 us; speedup 1.0000x reference)
//
#include <hip/hip_runtime.h>
#include <float.h>
#include <math.h>

// Problem constants (fixed by reference)
#define NB    8
#define K1    2048
#define K2    8192
#define NADD  16
#define PP    128          // K1 / NUM_ADD
#define FEPS  1e-7f
#define CDW   0.1f

// chamfer tiling: 2048 blocks = 8 blocks/CU = 8 waves/SIMD (latency hiding)
#define OCH   128          // ori chunks
#define OCLEN (K2 / OCH)   // 64 ori points per chunk
#define KC    2            // adv halves
#define MPT   4            // adv points per thread (K1/KC/256) - 4 indep chains
#define CH_GRID  (OCH * KC * NB)   // 2048 chamfer blocks
#define FAR_GRID 64                // (b, cluster-pair) blocks
#define GRID_A   (CH_GRID + FAR_GRID)

// reduce grid: 256 blocks, each owns 64 adv points x all 128 chunks
#define RB_KB 32           // k-blocks per batch (64 points each)
#define RB_GRID (RB_KB * NB)       // 256 blocks

// ws layout (float offsets)
#define PMIN_OFF 0
#define PMIN_SZ  (OCH * NB * K1)          // 2,097,152 floats (8 MB)
#define FARW_OFF PMIN_SZ
#define CHB_OFF  (FARW_OFF + NB * NADD)
#define CTR_OFF  (CHB_OFF + RB_GRID)

// ---------------------------------------------------------------------------
// Kernel A: fused chamfer-partial (blocks 0..2047) + farthest (blocks 2048..2111)
// __launch_bounds__(256, 8): force VGPR<=64 so 8 blocks/CU are resident.
// ---------------------------------------------------------------------------
__global__ __launch_bounds__(256, 8) void fused_a(const float* __restrict__ adv,
                                                  const float* __restrict__ ori,
                                                  float* __restrict__ pmins,
                                                  float* __restrict__ far,
                                                  unsigned int* __restrict__ ctr) {
    __shared__ float4 s4[192];        // chamfer: 64 float4; farthest: 768 floats
    __shared__ float sred[4];
    const int bid = blockIdx.x;
    const int t   = threadIdx.x;
    if (bid == 0 && t == 0) *ctr = 0u;   // reset kernel-B completion counter

    if (bid < CH_GRID) {
        // ---- chamfer partial: chunk oc of batch b vs adv half kc ----
        const int oc = bid & (OCH - 1);
        const int kc = (bid >> 7) & (KC - 1);
        const int b  = bid >> 8;

        if (t < OCLEN) {               // stage + pack this chunk's ori points
            const float* o = ori + ((size_t)b * K2 + oc * OCLEN + t) * 3;
            float x = o[0], y = o[1], z = o[2];
            s4[t] = make_float4(x, y, z, fmaf(x, x, fmaf(y, y, z * z)));
        }
        __syncthreads();

        float bx[MPT], by[MPT], bz[MPT], dmin[MPT];
        const int k0 = kc * (K1 / KC) + t;
#pragma unroll
        for (int j = 0; j < MPT; ++j) {
            const float* a = adv + (size_t)(b * K1 + k0 + 256 * j) * 3;
            bx[j] = -2.f * a[0];
            by[j] = -2.f * a[1];
            bz[j] = -2.f * a[2];
            dmin[j] = FLT_MAX;
        }

#pragma unroll 4
        for (int m = 0; m < OCLEN; ++m) {
            float4 o = s4[m];          // uniform address -> LDS broadcast, no conflict
#pragma unroll
            for (int j = 0; j < MPT; ++j)
                dmin[j] = fminf(dmin[j],
                                fmaf(bx[j], o.x, fmaf(by[j], o.y, fmaf(bz[j], o.z, o.w))));
        }

#pragma unroll
        for (int j = 0; j < MPT; ++j)  // coalesced
            pmins[((size_t)oc * NB + b) * K1 + k0 + 256 * j] = dmin[j];
    } else {
        // ---- farthest: block handles (b, cluster-pair), 128 threads/cluster ----
        const int fb = bid - CH_GRID;
        const int b  = fb >> 3;
        const int cp = fb & 7;
        const int g  = t >> 7;        // 0/1: which cluster of the pair
        const int p  = t & 127;
        const int ci = cp * 2 + g;

        float* sf = (float*)s4;       // [2][3][128]
        const float* c = adv + (size_t)(b * K1 + ci * PP) * 3;
        float px = c[p * 3 + 0], py = c[p * 3 + 1], pz = c[p * 3 + 2];
        float* sx = sf + g * 384;
        sx[p] = px; sx[128 + p] = py; sx[256 + p] = pz;
        __syncthreads();

        const float pxm = px - FEPS, pym = py - FEPS, pzm = pz - FEPS;
        float mx = 0.f;
#pragma unroll 8
        for (int q = 0; q < PP; ++q) {
            float dx = sx[q] - pxm;
            float dy = sx[128 + q] - pym;
            float dz = sx[256 + q] - pzm;
            mx = fmaxf(mx, fmaf(dx, dx, fmaf(dy, dy, dz * dz)));
        }
#pragma unroll
        for (int off = 32; off; off >>= 1) mx = fmaxf(mx, __shfl_down(mx, off, 64));
        if ((t & 63) == 0) sred[t >> 6] = mx;
        __syncthreads();
        if (t == 0)   far[b * NADD + cp * 2 + 0] = sqrtf(fmaxf(sred[0], sred[1]));
        if (t == 128) far[b * NADD + cp * 2 + 1] = sqrtf(fmaxf(sred[2], sred[3]));
    }
}

// ---------------------------------------------------------------------------
// Kernel B: min over 128 chunks + clamp + per-(b,kb) sum; last block combines.
// grid 256 blocks x 256 thr. Block (kb,b): adv points kb*64..kb*64+63.
// Thread t: point p=t&63, oc-strip s=t>>6 (32 chunks each).
// ---------------------------------------------------------------------------
__global__ __launch_bounds__(256) void reduce_b(const float* __restrict__ adv,
                                                const float* __restrict__ pmins,
                                                const float* __restrict__ far,
                                                const float* __restrict__ w,
                                                float* __restrict__ chbp,
                                                unsigned int* __restrict__ ctr,
                                                float* __restrict__ out) {
    __shared__ float smin[4][64];
    __shared__ float s[4];
    __shared__ unsigned int lastflag;
    const int t  = threadIdx.x;
    const int kb = blockIdx.x;
    const int b  = blockIdx.y;
    const int p  = t & 63;
    const int st = t >> 6;
    const int k  = kb * 64 + p;

    float m = FLT_MAX;
#pragma unroll 8
    for (int i = 0; i < OCH / 4; ++i) {   // 32 strided loads, coalesced per wave
        int oc = st * (OCH / 4) + i;
        m = fminf(m, pmins[((size_t)oc * NB + b) * K1 + k]);
    }
    smin[st][p] = m;
    __syncthreads();

    float sum = 0.f;
    if (t < 64) {
        float mm = fminf(fminf(smin[0][t], smin[1][t]), fminf(smin[2][t], smin[3][t]));
        const float* a = adv + (size_t)(b * K1 + kb * 64 + t) * 3;
        float ax = a[0], ay = a[1], az = a[2];
        float a2 = fmaf(ax, ax, fmaf(ay, ay, az * az));
        sum = fmaxf(a2 + mm, 0.f);
#pragma unroll
        for (int off = 32; off; off >>= 1) sum += __shfl_down(sum, off, 64);
    }

    if (t == 0) {
        __hip_atomic_store(&chbp[b * RB_KB + kb], sum,
                           __ATOMIC_RELEASE, __HIP_MEMORY_SCOPE_AGENT);
        unsigned int old = __hip_atomic_fetch_add(ctr, 1u,
                           __ATOMIC_ACQ_REL, __HIP_MEMORY_SCOPE_AGENT);
        lastflag = (old == RB_GRID - 1) ? 1u : 0u;
    }
    __syncthreads();
    if (!lastflag) return;

    // ---- final combine (single block, fixed order -> deterministic) ----
    float v = (CDW * 0.125f / K1) * w[t >> 5] *
              __hip_atomic_load(&chbp[t], __ATOMIC_ACQUIRE, __HIP_MEMORY_SCOPE_AGENT);
    if (t < 128) v += w[t >> 4] * far[t] * 0.125f;
#pragma unroll
    for (int off = 32; off; off >>= 1) v += __shfl_down(v, off, 64);
    __syncthreads();                 // protect s[] reuse
    if ((t & 63) == 0) s[t >> 6] = v;
    __syncthreads();
    if (t == 0) out[0] = s[0] + s[1] + s[2] + s[3];
}

// ---------------------------------------------------------------------------
extern "C" void kernel_launch(void* const* d_in, const int* in_sizes, int n_in,
                              void* d_out, int out_size, void* d_ws, size_t ws_size,
                              hipStream_t stream) {
    const float* adv = (const float*)d_in[0];
    const float* ori = (const float*)d_in[1];
    const float* w   = (const float*)d_in[2];
    float* ws    = (float*)d_ws;
    float* pmins = ws + PMIN_OFF;
    float* far   = ws + FARW_OFF;
    float* chbp  = ws + CHB_OFF;
    unsigned int* ctr = (unsigned int*)(ws + CTR_OFF);
    float* out   = (float*)d_out;

    fused_a<<<dim3(GRID_A), 256, 0, stream>>>(adv, ori, pmins, far, ctr);
    reduce_b<<<dim3(RB_KB, NB), 256, 0, stream>>>(adv, pmins, far, w, chbp, ctr, out);
}